// Round 2
// baseline (229.756 us; speedup 1.0000x reference)
//
#include <hip/hip_runtime.h>
#include <hip/hip_bf16.h>
#include <stdint.h>

#define L1DIM 1536
#define NOUT  144           // 128 (W1) + 16 (Wf) layer-1 outputs
#define MTILE 16            // rows per block (one bucket per block after sort)
#define BK    128           // K per staged slab
#define NITER (L1DIM / BK)  // 12
#define NBUF  4             // A slabs (prefetch distance 2 + WAR slack)
#define PERMN 16512         // 1032 * 16 (worst-case padded rows)
#define GMAIN 1032

typedef __bf16 bf16;
typedef __bf16 bf16x8 __attribute__((ext_vector_type(8)));
typedef float  floatx4 __attribute__((ext_vector_type(4)));

// ---------------------------------------------------------------------------
// K1: fused weight-pack + bucket histogram + perm init.
//   blocks 0..107  : pack [W1;Wf] -> pw in MFMA B-fragment order (unchanged)
//   blocks 108..171: perm[i]=-1 init; per-wave-aggregated histogram -> meta[1+b]
// meta layout (ints): [0]=padded_total  [1..8]=hist  [9..16]=offset/cursor
// ---------------------------------------------------------------------------
__global__ void k_pack_hist(const float* __restrict__ W1,
                            const float* __restrict__ Wf,
                            bf16* __restrict__ pw,
                            const int* __restrict__ lsidx,
                            int* __restrict__ perm,
                            int* __restrict__ meta) {
    const int gb = blockIdx.x;
    if (gb < 108) {
        int t = gb * 256 + threadIdx.x;      // 0 .. 27647
        int n = t / 192;                     // output feature 0..143
        int o = t % 192;                     // k-octet 0..191
        const float* src = (n < 128) ? (W1 + (size_t)n * L1DIM + o * 8)
                                     : (Wf + (size_t)(n - 128) * L1DIM + o * 8);
        float4 s0 = ((const float4*)src)[0];
        float4 s1 = ((const float4*)src)[1];
        bf16x8 v;
        v[0] = (bf16)s0.x; v[1] = (bf16)s0.y; v[2] = (bf16)s0.z; v[3] = (bf16)s0.w;
        v[4] = (bf16)s1.x; v[5] = (bf16)s1.y; v[6] = (bf16)s1.z; v[7] = (bf16)s1.w;
        *(bf16x8*)(pw + ((size_t)o * NOUT + n) * 8) = v;
    } else {
        const int i  = (gb - 108) * 256 + threadIdx.x;   // 0..16383
        perm[i] = -1;
        if (i < PERMN - 16384) perm[16384 + i] = -1;
        const int mb = lsidx[i];
        const int ln = threadIdx.x & 63;
#pragma unroll
        for (int b = 0; b < 8; b++) {
            unsigned long long m = __ballot(mb == b);
            if (m && ln == (__ffsll(m) - 1))
                atomicAdd(&meta[1 + b], (int)__popcll(m));
        }
    }
}

// K2: per-bucket padded offsets (pad each bucket's rows to a multiple of 16)
__global__ void k_offsets(int* __restrict__ meta) {
    if (threadIdx.x == 0 && blockIdx.x == 0) {
        int o = 0;
#pragma unroll
        for (int b = 0; b < 8; b++) {
            meta[9 + b] = o;
            o += (meta[1 + b] + 15) & ~15;
        }
        meta[0] = o;
    }
}

// K3: scatter row indices into perm, wave-aggregated atomics on cursors
__global__ void k_scatter(const int* __restrict__ lsidx,
                          int* __restrict__ perm,
                          int* __restrict__ meta) {
    const int i  = blockIdx.x * 256 + threadIdx.x;  // 0..16383
    const int mb = lsidx[i];
    const int ln = threadIdx.x & 63;
#pragma unroll
    for (int b = 0; b < 8; b++) {
        unsigned long long m = __ballot(mb == b);
        if (mb == b) {
            int leader = __ffsll(m) - 1;
            int base = 0;
            if (ln == leader) base = atomicAdd(&meta[9 + b], (int)__popcll(m));
            base = __shfl(base, leader);
            int pos = base + (int)__popcll(m & ((1ull << ln) - 1));
            perm[pos] = i;
        }
    }
}

__device__ __forceinline__ void gload_lds16(const void* g, void* l) {
    __builtin_amdgcn_global_load_lds(
        (const __attribute__((address_space(1))) void*)g,
        (__attribute__((address_space(3))) void*)l, 16, 0, 0);
}

__device__ __forceinline__ bf16x8 cvt8(float4 a, float4 b) {
    bf16x8 r;
    r[0] = (bf16)a.x; r[1] = (bf16)a.y; r[2] = (bf16)a.z; r[3] = (bf16)a.w;
    r[4] = (bf16)b.x; r[5] = (bf16)b.y; r[6] = (bf16)b.z; r[7] = (bf16)b.w;
    return r;
}

// ---------------------------------------------------------------------------
// Main kernel. Blocks own 16 bucket-sorted rows (single bucket + Wf => only
// 2 MFMA tiles). T3+T4 pipeline: 4 A-slabs, prefetch distance 2, B fragments
// register-prefetched 2 iters ahead (3-slot rotation, fully unrolled), counted
// s_waitcnt vmcnt(6) + raw s_barrier -- never a vmcnt(0) drain in the loop.
// FIFO accounting per iter (issue order: [ds_reads], stage(k+2)=2, B(k+2)=2):
//   top of iter k: newer-than-stage(k) = B(k)+stage(k+1)+B(k+1) = 6 -> vmcnt(6)
//   (last iter: newer-than-stage(11) = B(11) = 2 -> vmcnt(2))
// B(k) completion before MFMA is compiler-inserted (tracked VGPR loads).
// ---------------------------------------------------------------------------
__global__ __launch_bounds__(256, 4) void layerstacks_main(
    const float* __restrict__ x, const int* __restrict__ lsidx,
    const bf16* __restrict__ pw, const int* __restrict__ perm,
    const int* __restrict__ meta,
    const float* __restrict__ b1, const float* __restrict__ bf_,
    const float* __restrict__ W2, const float* __restrict__ b2,
    const float* __restrict__ Wo, const float* __restrict__ bo,
    float* __restrict__ out)
{
    __shared__ float la[NBUF][MTILE * BK];   // 32 KiB; reused as epilogue smem

    const int tid  = threadIdx.x;
    const int wv   = tid >> 6;               // wave id == k-quarter
    const int ln   = tid & 63;
    const int quad = ln >> 4;
    const int lm   = ln & 15;

    const int R0 = blockIdx.x * MTILE;
    if (R0 >= meta[0]) return;               // beyond padded total

    const int bkt = lsidx[perm[R0]];         // block-uniform (sorted; row 0 real)

    // ---- A staging lane geometry: instr j covers rows 2j,2j+1 of the slab.
    // lane -> row 2j+(ln>>5), lds slot ln&31, global chunk (ln&31)^(row&7).
    const int sro = ln >> 5;
    const int sch = ln & 31;
    const int r0r = 4 * wv + sro;            // jj=0 row
    const int r1r = 4 * wv + 2 + sro;        // jj=1 row
    int pr0 = perm[R0 + r0r]; if (pr0 < 0) pr0 = 0;   // pad rows read row 0
    int pr1 = perm[R0 + r1r]; if (pr1 < 0) pr1 = 0;
    const float* g0 = x + (size_t)pr0 * L1DIM + ((sch ^ (r0r & 7)) << 2);
    const float* g1 = x + (size_t)pr1 * L1DIM + ((sch ^ (r1r & 7)) << 2);

#define STAGE(buf_, ki_)                                                \
    {                                                                   \
        gload_lds16(g0 + (size_t)(ki_) * BK, &la[buf_][r0r * BK + sch * 4]); \
        gload_lds16(g1 + (size_t)(ki_) * BK, &la[buf_][r1r * BK + sch * 4]); \
    }

#define BLOAD(ki_, slot_)                                               \
    {                                                                   \
        const bf16* bb = pw + (size_t)((ki_) * 16 + wv * 4 + quad) * (NOUT * 8); \
        bs[slot_][0] = *(const bf16x8*)(bb + (bkt * 16 + lm) * 8);      \
        bs[slot_][1] = *(const bf16x8*)(bb + (128 + lm) * 8);           \
    }

    bf16x8  bs[3][2];
    floatx4 acc0 = (floatx4){0.f, 0.f, 0.f, 0.f};
    floatx4 acc1 = (floatx4){0.f, 0.f, 0.f, 0.f};

    const int c0 = wv * 8 + quad * 2;        // this lane's 16B chunk in a slab

    // prologue: two slabs + two B-sets in flight
    STAGE(0, 0) BLOAD(0, 0)
    STAGE(1, 1) BLOAD(1, 1)

#pragma unroll
    for (int ki = 0; ki < NITER; ki++) {
        if (ki == NITER - 1) asm volatile("s_waitcnt vmcnt(2)" ::: "memory");
        else                 asm volatile("s_waitcnt vmcnt(6)" ::: "memory");
        __builtin_amdgcn_s_barrier();        // slab ki visible to all waves
        __builtin_amdgcn_sched_barrier(0);

        const int row = lm;
        float4 a0 = *(const float4*)&la[ki & 3][row * BK + ((c0)     ^ (row & 7)) * 4];
        float4 a1 = *(const float4*)&la[ki & 3][row * BK + ((c0 + 1) ^ (row & 7)) * 4];

        if (ki < NITER - 2) { STAGE((ki + 2) & 3, ki + 2) BLOAD(ki + 2, (ki + 2) % 3) }

        bf16x8 af = cvt8(a0, a1);
        acc0 = __builtin_amdgcn_mfma_f32_16x16x32_bf16(af, bs[ki % 3][0], acc0, 0, 0, 0);
        acc1 = __builtin_amdgcn_mfma_f32_16x16x32_bf16(af, bs[ki % 3][1], acc1, 0, 0, 0);
    }

    // ------------------- epilogue (la reused as flat smem) -------------------
    // floats: [0..2111]  ep4[4][16][33]   (k-quarter partials)
    //         [2112..4031] W2 slice (64x30)   [4032..4095] Wo   [4096..4159] b2
    float* sm = (float*)la;

    __syncthreads();                          // everyone done with la slabs

    {   // per-wave partials (C layout: row=quad*4+r, col=lm)
#pragma unroll
        for (int r = 0; r < 4; r++) {
            const int row = quad * 4 + r;
            sm[(wv * 16 + row) * 33 + lm]      = acc0[r];
            sm[(wv * 16 + row) * 33 + 16 + lm] = acc1[r];
        }
    }
    // stage the block's W2/Wo/b2 slices (block-uniform bucket)
    {
        const float* w2src = W2 + (size_t)bkt * 64 * 30;
        for (int i = tid; i < 1920; i += 256) sm[2112 + i] = w2src[i];
        if (tid < 64) {
            sm[4032 + tid] = Wo[bkt * 64 + tid];
            sm[4096 + tid] = b2[bkt * 64 + tid];
        }
    }
    __syncthreads();

    {   // reduce 4 k-quarter partials into ep4[0]
        const int col = tid & 31;
        const int rr  = tid >> 5;             // 0..7
#pragma unroll
        for (int p = 0; p < 2; p++) {
            const int row = rr + p * 8;
            sm[row * 33 + col] = sm[row * 33 + col] + sm[528 + row * 33 + col]
                               + sm[1056 + row * 33 + col] + sm[1584 + row * 33 + col];
        }
    }
    __syncthreads();

    // ---- final: 8 threads per row, 16 rows (threads 0..127) ----
    if (tid < 128) {
        const int er  = tid >> 3;             // row in tile 0..15
        const int sub = tid & 7;              // output-group 0..7
        const int pr  = perm[R0 + er];        // original row (or -1 pad)
        if (pr >= 0) {
            const float l1c15 = sm[er * 33 + 15] + b1[bkt * 16 + 15];
            const float l1f15 = sm[er * 33 + 31] + bf_[15];

            float l1x[30];
#pragma unroll
            for (int j = 0; j < 15; j++) {
                float tj = (sm[er * 33 + j] + b1[bkt * 16 + j])
                         + (sm[er * 33 + 16 + j] + bf_[j]);
                float sq = tj * tj * (127.0f / 128.0f);
                l1x[j]      = fminf(fmaxf(sq, 0.f), 1.f);
                l1x[15 + j] = fminf(fmaxf(tj, 0.f), 1.f);
            }

            float part = 0.f;
#pragma unroll
            for (int o = 0; o < 8; o++) {
                const int ol = sub * 8 + o;
                const float* wrow = &sm[2112 + ol * 30];
                float a = sm[4096 + ol];
#pragma unroll
                for (int j2 = 0; j2 < 15; j2++) {
                    float2 w = *(const float2*)&wrow[2 * j2];
                    a += l1x[2 * j2] * w.x + l1x[2 * j2 + 1] * w.y;
                }
                a = fminf(fmaxf(a, 0.f), 1.f);
                part += a * sm[4032 + ol];
            }
            part += __shfl_xor(part, 1);
            part += __shfl_xor(part, 2);
            part += __shfl_xor(part, 4);
            if (sub == 0) out[pr] = part + bo[bkt] + l1c15 + l1f15;
        }
    }
#undef STAGE
#undef BLOAD
}

extern "C" void kernel_launch(void* const* d_in, const int* in_sizes, int n_in,
                              void* d_out, int out_size, void* d_ws, size_t ws_size,
                              hipStream_t stream) {
    const float* x   = (const float*)d_in[0];
    const int*   idx = (const int*)  d_in[1];
    const float* W1  = (const float*)d_in[2];
    const float* b1  = (const float*)d_in[3];
    const float* Wf  = (const float*)d_in[4];
    const float* bf  = (const float*)d_in[5];
    const float* W2  = (const float*)d_in[6];
    const float* b2  = (const float*)d_in[7];
    const float* Wo  = (const float*)d_in[8];
    const float* bo  = (const float*)d_in[9];
    float* out = (float*)d_out;

    // workspace: pw (442368 B) | perm (16512 ints) | meta (17 ints)
    bf16* pw   = (bf16*)d_ws;
    int*  perm = (int*)((char*)d_ws + 442368);
    int*  meta = perm + PERMN;

    hipMemsetAsync(meta, 0, 17 * sizeof(int), stream);
    k_pack_hist<<<dim3(172), dim3(256), 0, stream>>>(W1, Wf, pw, idx, perm, meta);
    k_offsets <<<dim3(1),   dim3(64),  0, stream>>>(meta);
    k_scatter <<<dim3(64),  dim3(256), 0, stream>>>(idx, perm, meta);
    layerstacks_main<<<dim3(GMAIN), dim3(256), 0, stream>>>(
        x, idx, pw, perm, meta, b1, bf, W2, b2, Wo, bo, out);
}